// Round 1
// baseline (174.529 us; speedup 1.0000x reference)
//
#include <hip/hip_runtime.h>
#include <hip/hip_bf16.h>

#define N_FEAT 128     // D_FEAT == UNITS == 128
#define EPT 8          // edges per thread in partition passes
#define CHUNK 2048     // 256 threads * EPT
#define BSHIFT 8       // bucket = node >> 8  (bucket range = 256 nodes)
#define MAXRANGE 256
#define CAP 8192       // per-bucket slot capacity (expected 4096 +- 64; 60-sigma margin)
#define LSTR 66        // LDS row stride in dwords (=132 bf16) for the pooled tile
#define PA_BLOCKS 1024 // streaming-normalize grid (R11: was 196 fused blocks)

typedef short bf16x8 __attribute__((ext_vector_type(8)));
typedef float f32x4  __attribute__((ext_vector_type(4)));

__device__ __forceinline__ unsigned short f2bf_rtne(float f) {
    unsigned u = __float_as_uint(f);
    u += 0x7fffu + ((u >> 16) & 1u);
    return (unsigned short)(u >> 16);
}
__device__ __forceinline__ float bf2f(unsigned short h) {
    return __uint_as_float((unsigned)h << 16);
}

// ---------------------------------------------------------------------------
// K1: scatter into fixed-capacity target buckets. R11: source-side bucket
// sort (cs/ss scan, lds_sp, srcB) DELETED — it existed only to compute
// out-degree. Replaced by direct global atomicAdd into degS[N] (~800k
// fire-and-forget L2 atomics). Halves LDS atomics, drops one full
// 16-barrier scan and 0.8 MB of scattered byte writes per run.
// ---------------------------------------------------------------------------
__global__ __launch_bounds__(256) void scatter_kernel(const int* __restrict__ source,
                                                      const int* __restrict__ target,
                                                      int* __restrict__ curT,
                                                      int* __restrict__ degS,
                                                      unsigned int* __restrict__ pairsT,
                                                      int E, int NB) {
    __shared__ unsigned int lds_pairs[CHUNK];    // 8 KB
    __shared__ int ct[MAXRANGE];
    __shared__ int st[MAXRANGE];
    __shared__ int gt[MAXRANGE];
    int tid = threadIdx.x, b = blockIdx.x;
    int base = b * CHUNK;
    int cnt = E - base; if (cnt > CHUNK) cnt = CHUNK;

    int rs[EPT], rt[EPT];
    ct[tid] = 0;
    __syncthreads();
    #pragma unroll
    for (int j = 0; j < EPT; ++j) {
        int e = base + j * 256 + tid;
        if (e < E) {
            int s = source[e], t = target[e];
            rs[j] = s; rt[j] = t;
            atomicAdd(&ct[t >> BSHIFT], 1);
            atomicAdd(&degS[s], 1);              // out-degree, direct to global
        }
    }
    __syncthreads();
    int vt = ct[tid];
    st[tid] = vt;
    __syncthreads();
    #pragma unroll
    for (int off = 1; off < 256; off <<= 1) {
        int t1 = (tid >= off) ? st[tid - off] : 0;
        __syncthreads();
        st[tid] += t1;
        __syncthreads();
    }
    int et = st[tid] - vt;
    int gT = 0;
    if (tid < NB && vt) gT = atomicAdd(&curT[tid], vt);
    __syncthreads();
    st[tid] = et; ct[tid] = et; gt[tid] = gT;
    __syncthreads();
    #pragma unroll
    for (int j = 0; j < EPT; ++j) {
        int e = base + j * 256 + tid;
        if (e < E) {
            int t = rt[j];
            int k = t >> BSHIFT;
            int p = atomicAdd(&ct[k], 1);
            lds_pairs[p] = (unsigned)rs[j] | ((unsigned)t << 16);
        }
    }
    __syncthreads();
    for (int i = tid; i < cnt; i += 256) {
        unsigned w = lds_pairs[i];
        int k = w >> 24;
        pairsT[(size_t)k * CAP + gt[k] + (i - st[k])] = w;
    }
}

// ---------------------------------------------------------------------------
// K2: fused prep. R11: pass A (x -> normalized bf16) no longer needs the
// srcB histogram — it reads degS directly and is now a pure streaming
// grid-stride pass over PA_BLOCKS blocks (was 196 blocks, <1 block/CU).
// Pass B (target CSR) and pass C (W hi/lo split) unchanged.
// ---------------------------------------------------------------------------
__global__ __launch_bounds__(256) void prep_kernel(const unsigned int* __restrict__ pairsT,
                                                   const int* __restrict__ curT,
                                                   const int* __restrict__ degS,
                                                   const float* __restrict__ x,
                                                   const float* __restrict__ W,
                                                   unsigned short* __restrict__ xb,
                                                   int2* __restrict__ offs,
                                                   int* __restrict__ elist,
                                                   float* __restrict__ ri,
                                                   unsigned short* __restrict__ Whi,
                                                   unsigned short* __restrict__ Wlo,
                                                   int N, int NB) {
    __shared__ int hist[MAXRANGE];
    __shared__ int sb[MAXRANGE];
    __shared__ int excl[MAXRANGE];
    __shared__ int cur[MAXRANGE];
    int tid = threadIdx.x, b = blockIdx.x;

    if (b < NB) {
        // ---- pass B: per-bucket target CSR (offs, ri, elist) ----
        int bb = b;
        hist[tid] = 0; cur[tid] = 0;
        __syncthreads();
        int cnt = curT[bb];
        int gbase = bb * CAP;
        for (int i = tid; i < cnt; i += 256)
            atomicAdd(&hist[(pairsT[(size_t)gbase + i] >> 16) & 255], 1);
        __syncthreads();
        int deg = hist[tid];
        sb[tid] = deg;
        __syncthreads();
        #pragma unroll
        for (int off = 1; off < 256; off <<= 1) {
            int t = (tid >= off) ? sb[tid - off] : 0;
            __syncthreads();
            sb[tid] += t;
            __syncthreads();
        }
        excl[tid] = sb[tid] - deg;
        __syncthreads();
        int node = (bb << BSHIFT) + tid;
        if (node < N) {
            int st0 = gbase + excl[tid];
            offs[node] = make_int2(st0, st0 + deg);
            int d = deg; if (d < 1) d = 1;
            ri[node] = rsqrtf((float)d);
        }
        for (int i = tid; i < cnt; i += 256) {
            unsigned w = pairsT[(size_t)gbase + i];
            int tl = (w >> 16) & 255;
            int pos = atomicAdd(&cur[tl], 1);
            elist[gbase + excl[tl] + pos] = (int)(w & 0xFFFFu);
        }
    } else if (b < NB + 8) {
        // ---- pass C: W -> bf16 hi/lo in MFMA fragment order ----
        int idx = (b - NB) * 256 + tid;
        int lane = idx & 63;
        int ks = (idx >> 6) & 3;
        int ct2 = idx >> 8;
        int n  = ct2 * 16 + (lane & 15);
        int k0 = ks * 32 + (lane >> 4) * 8;
        unsigned short h[8], l[8];
        #pragma unroll
        for (int j = 0; j < 8; ++j) {
            float w = W[(k0 + j) * N_FEAT + n];
            unsigned short hh = f2bf_rtne(w);
            h[j] = hh;
            l[j] = f2bf_rtne(w - bf2f(hh));
        }
        size_t off = (size_t)idx * 8;
        *(ushort4*)(Whi + off)     = make_ushort4(h[0], h[1], h[2], h[3]);
        *(ushort4*)(Whi + off + 4) = make_ushort4(h[4], h[5], h[6], h[7]);
        *(ushort4*)(Wlo + off)     = make_ushort4(l[0], l[1], l[2], l[3]);
        *(ushort4*)(Wlo + off + 4) = make_ushort4(l[4], l[5], l[6], l[7]);
    } else {
        // ---- pass A: streaming x * rsqrt(degS) -> bf16 xb ----
        int pb = b - NB - 8;
        int total = N * (N_FEAT / 4);                 // float4 granules
        const float4* xr = (const float4*)x;
        ushort4* xo = (ushort4*)xb;
        for (int i = pb * 256 + tid; i < total; i += PA_BLOCKS * 256) {
            int row = i >> 5;                         // 32 float4 per row
            int d = degS[row]; if (d < 1) d = 1;
            float s = rsqrtf((float)d);
            float4 v = xr[i];
            xo[i] = make_ushort4(f2bf_rtne(s * v.x), f2bf_rtne(s * v.y),
                                 f2bf_rtne(s * v.z), f2bf_rtne(s * v.w));
        }
    }
}

// Accumulate one gathered dword (2 bf16 feats) into a float2.
#define ACC_ROW(u, a) { a.x += __uint_as_float((u) << 16); \
                        a.y += __uint_as_float((u) & 0xffff0000u); }

// ---------------------------------------------------------------------------
// K3: FUSED agg + gemm. R11 change: gather widened to 4 edges per VMEM
// instruction — quarter-wave q owns edge j+4s+q, each lane loads dwordx4
// (16 B/lane, 8 feats). Per 16-edge batch: 4 gathers + 4 broadcast elist
// loads (was 16 gathers + 16 scalar loads). Cross-quarter shfl_xor(16/32)
// reduction recombines; quad 0 writes the SAME LDS layout as before, so
// the MFMA phase is untouched.
// ---------------------------------------------------------------------------
__global__ __launch_bounds__(256) void agg_gemm_kernel(const unsigned short* __restrict__ xb,
                                                       const int* __restrict__ elist,
                                                       const int2* __restrict__ offs,
                                                       const float* __restrict__ ri,
                                                       const unsigned short* __restrict__ Whi,
                                                       const unsigned short* __restrict__ Wlo,
                                                       const float* __restrict__ bias,
                                                       float* __restrict__ out,
                                                       int N) {
    __shared__ unsigned int hi_l[16 * LSTR];   // 4.2 KB
    __shared__ unsigned int lo_l[16 * LSTR];   // 4.2 KB
    int wave = threadIdx.x >> 6;
    int lane = threadIdx.x & 63;
    int quad = lane >> 4;       // quarter-wave id: which edge of the 4-slot
    int k16  = lane & 15;       // feat granule within the row (8 feats)
    int rowbase = blockIdx.x * 16;
    const uint4* xr = (const uint4*)xb;        // 16 granules per 128-feat row

    // ---------------- phase 1: pooled rows -> LDS (bf16 hi/lo) -------------
    #pragma unroll
    for (int i = 0; i < 4; ++i) {
        int r = wave * 4 + i;
        int node = rowbase + r;
        if (node < N) {
            int2 oe = offs[node];
            int start = __builtin_amdgcn_readfirstlane(oe.x);
            int end   = __builtin_amdgcn_readfirstlane(oe.y);
            float rr = ri[node];
            float2 a0 = make_float2(0.f, 0.f), a1 = a0, a2 = a0, a3 = a0;
            int j = start;
            for (; j + 16 <= end; j += 16) {
                int e0 = elist[j + quad];           // broadcast within quarter
                int e1 = elist[j + 4 + quad];
                int e2 = elist[j + 8 + quad];
                int e3 = elist[j + 12 + quad];
                uint4 u0 = xr[e0 * 16 + k16];
                uint4 u1 = xr[e1 * 16 + k16];
                uint4 u2 = xr[e2 * 16 + k16];
                uint4 u3 = xr[e3 * 16 + k16];
                ACC_ROW(u0.x, a0) ACC_ROW(u0.y, a1) ACC_ROW(u0.z, a2) ACC_ROW(u0.w, a3)
                ACC_ROW(u1.x, a0) ACC_ROW(u1.y, a1) ACC_ROW(u1.z, a2) ACC_ROW(u1.w, a3)
                ACC_ROW(u2.x, a0) ACC_ROW(u2.y, a1) ACC_ROW(u2.z, a2) ACC_ROW(u2.w, a3)
                ACC_ROW(u3.x, a0) ACC_ROW(u3.y, a1) ACC_ROW(u3.z, a2) ACC_ROW(u3.w, a3)
            }
            for (; j + 4 <= end; j += 4) {
                int e = elist[j + quad];
                uint4 u = xr[e * 16 + k16];
                ACC_ROW(u.x, a0) ACC_ROW(u.y, a1) ACC_ROW(u.z, a2) ACC_ROW(u.w, a3)
            }
            if (j < end) {                           // masked tail: 1-3 edges
                int jj = j + quad;
                bool valid = jj < end;
                int e = valid ? elist[jj] : 0;       // predicated load, safe
                uint4 u = xr[e * 16 + k16];
                if (valid) {
                    ACC_ROW(u.x, a0) ACC_ROW(u.y, a1) ACC_ROW(u.z, a2) ACC_ROW(u.w, a3)
                }
            }
            // cross-quarter reduce: lanes {k16, k16+16, k16+32, k16+48}
            float v[8] = { a0.x, a0.y, a1.x, a1.y, a2.x, a2.y, a3.x, a3.y };
            #pragma unroll
            for (int t = 0; t < 8; ++t) {
                v[t] += __shfl_xor(v[t], 16);
                v[t] += __shfl_xor(v[t], 32);
                v[t] *= rr;
            }
            if (quad == 0) {
                unsigned hp[4], lp[4];
                #pragma unroll
                for (int t = 0; t < 4; ++t) {
                    unsigned short h0 = f2bf_rtne(v[2 * t]);
                    unsigned short h1 = f2bf_rtne(v[2 * t + 1]);
                    unsigned short l0 = f2bf_rtne(v[2 * t]     - bf2f(h0));
                    unsigned short l1 = f2bf_rtne(v[2 * t + 1] - bf2f(h1));
                    hp[t] = (unsigned)h0 | ((unsigned)h1 << 16);
                    lp[t] = (unsigned)l0 | ((unsigned)l1 << 16);
                }
                unsigned int* hd = hi_l + r * LSTR + 4 * k16;  // dword d = feats 2d,2d+1
                unsigned int* ld = lo_l + r * LSTR + 4 * k16;
                hd[0] = hp[0]; hd[1] = hp[1]; hd[2] = hp[2]; hd[3] = hp[3];
                ld[0] = lp[0]; ld[1] = lp[1]; ld[2] = lp[2]; ld[3] = lp[3];
            }
        } else if (quad == 0) {
            unsigned int* hd = hi_l + r * LSTR + 4 * k16;
            unsigned int* ld = lo_l + r * LSTR + 4 * k16;
            hd[0] = 0; hd[1] = 0; hd[2] = 0; hd[3] = 0;
            ld[0] = 0; ld[1] = 0; ld[2] = 0; ld[3] = 0;
        }
    }
    __syncthreads();

    // ---------------- phase 2: 16x128 MFMA tile (unchanged) ----------------
    bf16x8 Ahi[4], Alo[4];
    int m = k16;
    #pragma unroll
    for (int ks = 0; ks < 4; ++ks) {
        int a = m * LSTR + ks * 16 + quad * 4;
        Ahi[ks] = *(const bf16x8*)(hi_l + a);
        Alo[ks] = *(const bf16x8*)(lo_l + a);
    }
    const bf16x8* BH = (const bf16x8*)Whi;
    const bf16x8* BL = (const bf16x8*)Wlo;

    #pragma unroll
    for (int c = 0; c < 2; ++c) {
        int ct = wave * 2 + c;
        f32x4 acc = {0.f, 0.f, 0.f, 0.f};
        #pragma unroll
        for (int ks = 0; ks < 4; ++ks) {
            bf16x8 bh = BH[(ct * 4 + ks) * 64 + lane];
            bf16x8 bl = BL[(ct * 4 + ks) * 64 + lane];
            acc = __builtin_amdgcn_mfma_f32_16x16x32_bf16(Ahi[ks], bh, acc, 0, 0, 0);
            acc = __builtin_amdgcn_mfma_f32_16x16x32_bf16(Alo[ks], bh, acc, 0, 0, 0);
            acc = __builtin_amdgcn_mfma_f32_16x16x32_bf16(Ahi[ks], bl, acc, 0, 0, 0);
        }
        int colc = ct * 16 + m;
        float bv = bias[colc];
        #pragma unroll
        for (int reg = 0; reg < 4; ++reg) {
            int rr2 = rowbase + quad * 4 + reg;
            if (rr2 < N)
                out[(size_t)rr2 * N_FEAT + colc] = fmaxf(acc[reg] + bv, 0.f);
        }
    }
}

// ---------------------------------------------------------------------------
extern "C" void kernel_launch(void* const* d_in, const int* in_sizes, int n_in,
                              void* d_out, int out_size, void* d_ws, size_t ws_size,
                              hipStream_t stream) {
    const float* x      = (const float*)d_in[0];
    const int*   source = (const int*)d_in[1];
    const int*   target = (const int*)d_in[2];
    const float* W      = (const float*)d_in[3];
    const float* bias   = (const float*)d_in[4];
    float*       out    = (float*)d_out;

    const int N = in_sizes[0] / N_FEAT;   // 50000
    const int E = in_sizes[1];            // 800000

    const int NB   = (N + MAXRANGE - 1) >> BSHIFT;  // 196
    const int NBLK = (E + CHUNK - 1) / CHUNK;       // 391

    uintptr_t p = (uintptr_t)d_ws;
    auto carve = [&](size_t bytes) {
        p = (p + 255) & ~(uintptr_t)255;
        uintptr_t r = p;
        p += bytes;
        return (void*)r;
    };
    int*            curT    = (int*)carve((size_t)(NB + N) * sizeof(int)); // curT|degS (memset)
    int*            degS    = curT + NB;
    unsigned int*   pairsT  = (unsigned int*)carve((size_t)NB * CAP * sizeof(unsigned int));
    int*            elist   = (int*)carve((size_t)NB * CAP * sizeof(int) + 64); // +slack for tail
    float*          ri      = (float*)carve((size_t)N * sizeof(float));
    int2*           offs    = (int2*)carve((size_t)N * sizeof(int2));
    unsigned short* xb      = (unsigned short*)carve((size_t)N * N_FEAT * sizeof(unsigned short));
    unsigned short* Whi     = (unsigned short*)carve((size_t)N_FEAT * N_FEAT * sizeof(unsigned short));
    unsigned short* Wlo     = (unsigned short*)carve((size_t)N_FEAT * N_FEAT * sizeof(unsigned short));
    (void)ws_size; (void)n_in; (void)out_size;

    (void)hipMemsetAsync(curT, 0, (size_t)(NB + N) * sizeof(int), stream);

    scatter_kernel<<<NBLK, 256, 0, stream>>>(source, target, curT, degS, pairsT, E, NB);
    prep_kernel<<<NB + 8 + PA_BLOCKS, 256, 0, stream>>>(pairsT, curT, degS, x, W,
                                                        xb, offs, elist, ri, Whi, Wlo, N, NB);
    agg_gemm_kernel<<<(N + 15) / 16, 256, 0, stream>>>(xb, elist, offs, ri,
                                                       Whi, Wlo, bias, out, N);
}